// Round 6
// baseline (557.367 us; speedup 1.0000x reference)
//
#include <hip/hip_runtime.h>
#include <hip/hip_bf16.h>
#include <math.h>

#define B_ 2
#define T_ 2048
#define D_ 2048
#define H_ 16

typedef __attribute__((ext_vector_type(8))) short bf16x8;
typedef __attribute__((ext_vector_type(4))) float f32x4;
typedef unsigned short ushort_t;

// fp32 -> bf16 bits, round-to-nearest-even
__device__ __forceinline__ ushort_t f2bf(float f) {
    unsigned int u = __float_as_uint(f);
    u += 0x7fffu + ((u >> 16) & 1u);
    return (ushort_t)(u >> 16);
}

__device__ __forceinline__ void gl_lds16(const void* g, void* l) {
    __builtin_amdgcn_global_load_lds(
        (const __attribute__((address_space(1))) void*)g,
        (__attribute__((address_space(3))) void*)l, 16, 0, 0);
}

// ---------------------------------------------------------------------------
// fused x cvt + gate: one block per token row.
//   xbf[row][:] = bf16(x[row][:])
//   gate[row][h] = sigmoid(gate_logit[h] + x[row,:] . gate_w[:,h])
// ---------------------------------------------------------------------------
__global__ __launch_bounds__(256) void cvt_gate_kernel(
    const float* __restrict__ x, const float* __restrict__ gw,
    const float* __restrict__ glogit,
    ushort_t* __restrict__ xbf, float* __restrict__ gate)
{
    __shared__ float xs[2048];
    __shared__ float red[256];
    const int row = blockIdx.x, tid = threadIdx.x;

    const float4 a = *(const float4*)(x + (size_t)row * 2048 + tid * 8);
    const float4 b = *(const float4*)(x + (size_t)row * 2048 + tid * 8 + 4);
    unsigned int r0 = (unsigned int)f2bf(a.x) | ((unsigned int)f2bf(a.y) << 16);
    unsigned int r1 = (unsigned int)f2bf(a.z) | ((unsigned int)f2bf(a.w) << 16);
    unsigned int r2 = (unsigned int)f2bf(b.x) | ((unsigned int)f2bf(b.y) << 16);
    unsigned int r3 = (unsigned int)f2bf(b.z) | ((unsigned int)f2bf(b.w) << 16);
    *(uint4*)(xbf + (size_t)row * 2048 + tid * 8) = make_uint4(r0, r1, r2, r3);
    *(float4*)&xs[tid * 8] = a;
    *(float4*)&xs[tid * 8 + 4] = b;
    __syncthreads();

    const int h = tid & 15, chunk = tid >> 4;
    float acc = 0.f;
#pragma unroll 4
    for (int d0 = 0; d0 < 128; d0++) {
        const int d = chunk * 128 + d0;
        acc += xs[d] * gw[d * 16 + h];
    }
    red[tid] = acc;
    __syncthreads();
    for (int st = 8; st >= 1; st >>= 1) {
        if (chunk < st) red[chunk * 16 + h] += red[(chunk + st) * 16 + h];
        __syncthreads();
    }
    if (tid < 16) gate[row * 16 + tid] = 1.f / (1.f + expf(-(glogit[tid] + red[tid])));
}

// ---------------------------------------------------------------------------
// rope cos/sin table: tab[t*32+j] = (cos, sin)(t * 10000^(-j/32))
// ---------------------------------------------------------------------------
__global__ __launch_bounds__(256) void rope_table(float2* __restrict__ tab)
{
    const int gid = blockIdx.x * 256 + threadIdx.x;  // 65536
    const int j = gid & 31, t = gid >> 5;
    const float invf = exp2f((float)j * -0.41524101186091903f);
    const float ang = (float)t * invf;
    tab[gid] = make_float2(cosf(ang), sinf(ang));
}

// ---------------------------------------------------------------------------
// cvt + transpose: in[K][N] fp32 -> out[N][K] bf16. 64x64 LDS tile.
// ---------------------------------------------------------------------------
__global__ __launch_bounds__(256) void cvt_tr_bf16(
    const float* __restrict__ in, ushort_t* __restrict__ out, int K, int N)
{
    __shared__ float t[64][65];
    const int n0 = blockIdx.x * 64, k0 = blockIdx.y * 64;
    const int tx = threadIdx.x & 63, ty = threadIdx.x >> 6;
#pragma unroll
    for (int i = 0; i < 16; i++) {
        const int r = i * 4 + ty;
        t[r][tx] = in[(size_t)(k0 + r) * N + n0 + tx];
    }
    __syncthreads();
#pragma unroll
    for (int i = 0; i < 16; i++) {
        const int nn = i * 4 + ty;
        out[(size_t)(n0 + nn) * K + k0 + tx] = f2bf(t[tx][nn]);
    }
}

// 4 QK-projection weights (each [2048][1024]) in one launch; z selects source.
__global__ __launch_bounds__(256) void cvt_tr4_bf16(
    const float* __restrict__ s0, const float* __restrict__ s1,
    const float* __restrict__ s2, const float* __restrict__ s3,
    ushort_t* __restrict__ out)
{
    __shared__ float t[64][65];
    const int z = blockIdx.z;
    const float* in = (z == 0) ? s0 : (z == 1) ? s1 : (z == 2) ? s2 : s3;
    ushort_t* o = out + (size_t)z * 2097152;
    const int N = 1024, K = 2048;
    const int n0 = blockIdx.x * 64, k0 = blockIdx.y * 64;
    const int tx = threadIdx.x & 63, ty = threadIdx.x >> 6;
#pragma unroll
    for (int i = 0; i < 16; i++) {
        const int r = i * 4 + ty;
        t[r][tx] = in[(size_t)(k0 + r) * N + n0 + tx];
    }
    __syncthreads();
#pragma unroll
    for (int i = 0; i < 16; i++) {
        const int nn = i * 4 + ty;
        o[(size_t)(n0 + nn) * K + k0 + tx] = f2bf(t[tx][nn]);
    }
}

// ---------------------------------------------------------------------------
// Shared GEMM core (m97 structure): acc = A[M,K] @ BT[N,K]^T, 128x128 tile.
// ---------------------------------------------------------------------------
__device__ __forceinline__ void gemm_core(
    const ushort_t* __restrict__ Ab, const ushort_t* __restrict__ BTb,
    int K, int row0, int col0,
    ushort_t* As, ushort_t* Bs, f32x4 (&acc)[4][4], int w, int lane)
{
    const int lm = lane & 15, lk = (lane >> 4) << 3;
    const int wr = w >> 1, wc = w & 1;
#pragma unroll
    for (int m = 0; m < 4; m++)
#pragma unroll
        for (int n = 0; n < 4; n++) {
            acc[m][n][0] = 0.f; acc[m][n][1] = 0.f;
            acc[m][n][2] = 0.f; acc[m][n][3] = 0.f;
        }

    for (int k0 = 0; k0 < K; k0 += 32) {
        __syncthreads();
#pragma unroll
        for (int i = 0; i < 2; i++) {
            const int chunk = i * 4 + w;
            const int idx = chunk * 64 + lane;
            const int r = idx >> 2;
            const int c = (idx & 3) << 3;
            gl_lds16(Ab + (size_t)(row0 + r) * K + k0 + c, As + chunk * 512);
            gl_lds16(BTb + (size_t)(col0 + r) * K + k0 + c, Bs + chunk * 512);
        }
        __syncthreads();

        bf16x8 av[4], bv[4];
#pragma unroll
        for (int m = 0; m < 4; m++)
            av[m] = *(const bf16x8*)&As[(wr * 64 + m * 16 + lm) * 32 + lk];
#pragma unroll
        for (int n = 0; n < 4; n++)
            bv[n] = *(const bf16x8*)&Bs[(wc * 64 + n * 16 + lm) * 32 + lk];
        __builtin_amdgcn_s_setprio(1);
#pragma unroll
        for (int m = 0; m < 4; m++)
#pragma unroll
            for (int n = 0; n < 4; n++)
                acc[m][n] = __builtin_amdgcn_mfma_f32_16x16x32_bf16(
                    av[m], bv[n], acc[m][n], 0, 0, 0);
        __builtin_amdgcn_s_setprio(0);
    }
}

// bijective XCD swizzle (nwg % 8 == 0 for all our grids)
__device__ __forceinline__ void xcd_tile(int& row0, int& col0)
{
    const int o = blockIdx.y * gridDim.x + blockIdx.x;
    const int nwg = gridDim.x * gridDim.y;
    const int s = (o & 7) * (nwg >> 3) + (o >> 3);
    col0 = (s % gridDim.x) << 7;
    row0 = (s / gridDim.x) << 7;
}

// ---------------------------------------------------------------------------
// gemm_bf16_bt: fp32 row-major C (final output projection)
// ---------------------------------------------------------------------------
__global__ __launch_bounds__(256) void gemm_bf16_bt(
    const ushort_t* __restrict__ Ab, const ushort_t* __restrict__ BTb,
    float* __restrict__ C, int N, int K)
{
    __shared__ ushort_t As[4096];
    __shared__ ushort_t Bs[4096];
    const int tid = threadIdx.x;
    const int w = tid >> 6, lane = tid & 63;
    int row0, col0;
    xcd_tile(row0, col0);
    f32x4 acc[4][4];
    gemm_core(Ab, BTb, K, row0, col0, As, Bs, acc, w, lane);

    const int wr = w >> 1, wc = w & 1;
    const int lm = lane & 15;
#pragma unroll
    for (int m = 0; m < 4; m++) {
        const int rowb = row0 + wr * 64 + m * 16 + ((lane >> 4) << 2);
#pragma unroll
        for (int n = 0; n < 4; n++) {
            const int col = col0 + wc * 64 + n * 16 + lm;
#pragma unroll
            for (int r = 0; r < 4; r++)
                C[(size_t)(rowb + r) * N + col] = acc[m][n][r];
        }
    }
}

// ---------------------------------------------------------------------------
// gemm_bf16_bf16out: bf16 row-major C (V projection)
// ---------------------------------------------------------------------------
__global__ __launch_bounds__(256) void gemm_bf16_bf16out(
    const ushort_t* __restrict__ Ab, const ushort_t* __restrict__ BTb,
    ushort_t* __restrict__ C, int N, int K)
{
    __shared__ ushort_t As[4096];
    __shared__ ushort_t Bs[4096];
    const int tid = threadIdx.x;
    const int w = tid >> 6, lane = tid & 63;
    int row0, col0;
    xcd_tile(row0, col0);
    f32x4 acc[4][4];
    gemm_core(Ab, BTb, K, row0, col0, As, Bs, acc, w, lane);

    const int wr = w >> 1, wc = w & 1;
    const int lm = lane & 15;
#pragma unroll
    for (int m = 0; m < 4; m++) {
        const int rowb = row0 + wr * 64 + m * 16 + ((lane >> 4) << 2);
#pragma unroll
        for (int n = 0; n < 4; n++) {
            const int col = col0 + wc * 64 + n * 16 + lm;
#pragma unroll
            for (int r = 0; r < 4; r++)
                C[(size_t)(rowb + r) * N + col] = f2bf(acc[m][n][r]);
        }
    }
}

// ---------------------------------------------------------------------------
// gemm_qk_fused: QK projection with fused rope/gate/bf16/K-swizzle epilogue.
// cols [0,1024)=qs, [1024,2048)=ks, [2048,3072)=qg, [3072,4096)=kg.
// ---------------------------------------------------------------------------
__global__ __launch_bounds__(256) void gemm_qk_fused(
    const ushort_t* __restrict__ Ab, const ushort_t* __restrict__ BTb,
    const float* __restrict__ GATE, const float2* __restrict__ tab,
    ushort_t* __restrict__ Qb, ushort_t* __restrict__ Kb, int K)
{
    __shared__ ushort_t As[4096];
    __shared__ ushort_t Bs[4096];
    const int tid = threadIdx.x;
    const int w = tid >> 6, lane = tid & 63;
    int row0, col0;
    xcd_tile(row0, col0);
    f32x4 acc[4][4];
    gemm_core(Ab, BTb, K, row0, col0, As, Bs, acc, w, lane);

    const int wr = w >> 1, wc = w & 1;
    const int lm = lane & 15, lg = lane >> 4;
    const int col_base = col0 + wc * 64;     // 64-aligned -> one head, one region
    const int region = col_base >> 10;       // 0=qs 1=ks 2=qg 3=kg
    const int h = (col_base >> 6) & 15;

#pragma unroll
    for (int m = 0; m < 4; m++) {
        const int rbase = row0 + wr * 64 + m * 16 + (lg << 2);
#pragma unroll
        for (int r = 0; r < 4; r++) {
            const int row = rbase + r;
            const int t = row & (T_ - 1);
            const int bq = row >> 11;
            const size_t obase = ((size_t)(bq * 16 + h) * 2048 + t) * 128;
            if (region == 0) {
                const float sc = GATE[row * 16 + h] * 0.125f;
#pragma unroll
                for (int n = 0; n < 4; n++)
                    Qb[obase + n * 16 + lm] = f2bf(acc[m][n][r] * sc);
            } else if (region == 1) {
                const int sw = (t & 7) << 3;
#pragma unroll
                for (int n = 0; n < 4; n++)
                    Kb[obase + ((n * 16 + lm) ^ sw)] = f2bf(acc[m][n][r]);
            } else if (region == 2) {
                const float sc = (1.f - GATE[row * 16 + h]) * 0.125f;
#pragma unroll
                for (int n = 0; n < 2; n++) {
                    const int j = n * 16 + lm;
                    const float2 cs = tab[t * 32 + j];
                    const float x1 = acc[m][n][r], x2 = acc[m][n + 2][r];
                    Qb[obase + 64 + j] = f2bf((x1 * cs.x - x2 * cs.y) * sc);
                    Qb[obase + 96 + j] = f2bf((x2 * cs.x + x1 * cs.y) * sc);
                }
            } else {
                const int sw = (t & 7) << 3;
#pragma unroll
                for (int n = 0; n < 2; n++) {
                    const int j = n * 16 + lm;
                    const float2 cs = tab[t * 32 + j];
                    const float x1 = acc[m][n][r], x2 = acc[m][n + 2][r];
                    Kb[obase + ((64 + j) ^ sw)] = f2bf(x1 * cs.x - x2 * cs.y);
                    Kb[obase + ((96 + j) ^ sw)] = f2bf(x2 * cs.x + x1 * cs.y);
                }
            }
        }
    }
}

// ---------------------------------------------------------------------------
// prep_v: Vbb bf16 [row][h*128+dv] -> Vt[bh][dv][t swizzled] bf16 (V^T).
// ---------------------------------------------------------------------------
__global__ __launch_bounds__(256) void prep_v(
    const ushort_t* __restrict__ Vbb, ushort_t* __restrict__ Vt)
{
    __shared__ ushort_t tile[64][65];
    const int t0 = blockIdx.x * 64, dv0 = blockIdx.y * 64, bh = blockIdx.z;
    const int b = bh >> 4, h = bh & 15;
    const int c = threadIdx.x & 63, rq = threadIdx.x >> 6;
#pragma unroll
    for (int i = 0; i < 16; i++) {
        const int r = i * 4 + rq;
        tile[r][c] = Vbb[(size_t)(b * T_ + t0 + r) * 2048 + h * 128 + dv0 + c];
    }
    __syncthreads();
#pragma unroll
    for (int i = 0; i < 16; i++) {
        const int dvr = i * 4 + rq;
        const int dv = dv0 + dvr;
        Vt[((size_t)bh * 128 + dv) * 2048 + t0 + (c ^ ((dv & 7) << 3))] = tile[c][dvr];
    }
}

// ---------------------------------------------------------------------------
// MFMA flash attention, causal-PAIRED: block (pair, bh) processes Q-tiles
// (15-pair) and (pair) sequentially -> every block does exactly 34 K-tiles.
// QBLK=128 (4 waves x 32 rows), KBLK=64, d=dv=128. Defer-max THR=8.
// ---------------------------------------------------------------------------
__global__ __launch_bounds__(256, 2) void attn_mfma(
    const ushort_t* __restrict__ Qb, const ushort_t* __restrict__ Kb,
    const ushort_t* __restrict__ Vt, ushort_t* __restrict__ OUT)
{
    __shared__ ushort_t Ks[64 * 128];   // [key][d_sw]  16KB
    __shared__ ushort_t Vs[128 * 64];   // [dv][k_sw]   16KB
    __shared__ ushort_t Ps[4][32 * 72]; // per-wave P, row stride 72  18KB

    const int tid = threadIdx.x;
    const int w = tid >> 6, l = tid & 63;
    const int lg = l >> 4, lm = l & 15;
    const int bh = blockIdx.y;
    const int pair = blockIdx.x;        // 0..7
    const size_t hb = (size_t)bh * 2048 * 128;
    const int b = bh >> 4, h = bh & 15;
    ushort_t* pw = &Ps[w][0];

    for (int half = 0; half < 2; half++) {
        const int tile = (half == 0) ? (15 - pair) : pair;   // heavy first
        const int t0 = tile << 7;

        bf16x8 qf[2][4];
#pragma unroll
        for (int m = 0; m < 2; m++)
#pragma unroll
            for (int ks = 0; ks < 4; ks++)
                qf[m][ks] = *(const bf16x8*)(Qb + hb +
                    (size_t)(t0 + w * 32 + m * 16 + lm) * 128 + ks * 32 + lg * 8);

        f32x4 o[2][8];
        float mi[2][4], li[2][4];
#pragma unroll
        for (int m = 0; m < 2; m++) {
#pragma unroll
            for (int r = 0; r < 4; r++) { mi[m][r] = -1e30f; li[m][r] = 0.f; }
#pragma unroll
            for (int nv = 0; nv < 8; nv++) {
                o[m][nv][0] = 0.f; o[m][nv][1] = 0.f;
                o[m][nv][2] = 0.f; o[m][nv][3] = 0.f;
            }
        }

        const int nkt = 2 * tile + 2;
        for (int kt = 0; kt < nkt; kt++) {
            const int s0 = kt << 6;
            __syncthreads();
#pragma unroll
            for (int rr = 0; rr < 4; rr++) {
                const int chunk = rr * 4 + w;
                gl_lds16(Kb + hb + (size_t)(s0 + chunk * 4 + lg) * 128 + lm * 8,
                         Ks + chunk * 512);
            }
#pragma unroll
            for (int rr = 0; rr < 4; rr++) {
                const int chunk = rr * 4 + w;
                gl_lds16(Vt + hb + (size_t)(chunk * 8 + (l >> 3)) * 2048 + s0 + (l & 7) * 8,
                         Vs + chunk * 512);
            }
            __syncthreads();

            // ---- S = Q . K^T ----
            f32x4 sacc[2][4];
#pragma unroll
            for (int m = 0; m < 2; m++)
#pragma unroll
                for (int n = 0; n < 4; n++) {
                    sacc[m][n][0] = 0.f; sacc[m][n][1] = 0.f;
                    sacc[m][n][2] = 0.f; sacc[m][n][3] = 0.f;
                }
#pragma unroll
            for (int ks = 0; ks < 4; ks++) {
                bf16x8 bfr[4];
#pragma unroll
                for (int n = 0; n < 4; n++) {
                    const int key = n * 16 + lm;
                    const int d = ks * 32 + lg * 8;
                    bfr[n] = *(const bf16x8*)&Ks[key * 128 + (d ^ ((key & 7) << 3))];
                }
                __builtin_amdgcn_s_setprio(1);
#pragma unroll
                for (int m = 0; m < 2; m++)
#pragma unroll
                    for (int n = 0; n < 4; n++)
                        sacc[m][n] = __builtin_amdgcn_mfma_f32_16x16x32_bf16(
                            qf[m][ks], bfr[n], sacc[m][n], 0, 0, 0);
                __builtin_amdgcn_s_setprio(0);
            }

            if (kt >= nkt - 2) {
#pragma unroll
                for (int m = 0; m < 2; m++)
#pragma unroll
                    for (int n = 0; n < 4; n++)
#pragma unroll
                        for (int r = 0; r < 4; r++) {
                            const int rowt = t0 + w * 32 + m * 16 + lg * 4 + r;
                            const int colt = s0 + n * 16 + lm;
                            if (colt > rowt) sacc[m][n][r] = -1e30f;
                        }
            }

            // ---- online softmax (defer-max THR=8) + P -> LDS (bf16) ----
#pragma unroll
            for (int m = 0; m < 2; m++) {
#pragma unroll
                for (int r = 0; r < 4; r++) {
                    float mt = fmaxf(fmaxf(sacc[m][0][r], sacc[m][1][r]),
                                     fmaxf(sacc[m][2][r], sacc[m][3][r]));
                    mt = fmaxf(mt, __shfl_xor(mt, 1));
                    mt = fmaxf(mt, __shfl_xor(mt, 2));
                    mt = fmaxf(mt, __shfl_xor(mt, 4));
                    mt = fmaxf(mt, __shfl_xor(mt, 8));
                    const float miold = mi[m][r];
                    if (mt > miold + 8.f) {      // rescale path
                        const float alpha = __expf(miold - mt);
                        li[m][r] *= alpha;
#pragma unroll
                        for (int nv = 0; nv < 8; nv++) o[m][nv][r] *= alpha;
                        mi[m][r] = mt;
                    }
                    const float mcur = mi[m][r];
                    float rs = 0.f;
#pragma unroll
                    for (int n = 0; n < 4; n++) {
                        const float p = __expf(sacc[m][n][r] - mcur);
                        sacc[m][n][r] = p;
                        rs += p;
                    }
                    rs += __shfl_xor(rs, 1);
                    rs += __shfl_xor(rs, 2);
                    rs += __shfl_xor(rs, 4);
                    rs += __shfl_xor(rs, 8);
                    li[m][r] += rs;
#pragma unroll
                    for (int n = 0; n < 4; n++)
                        pw[(m * 16 + lg * 4 + r) * 72 + n * 16 + lm] = f2bf(sacc[m][n][r]);
                }
            }

            // ---- O += P @ V ----
#pragma unroll
            for (int ks2 = 0; ks2 < 2; ks2++) {
                bf16x8 pa[2];
#pragma unroll
                for (int m = 0; m < 2; m++)
                    pa[m] = *(const bf16x8*)&pw[(m * 16 + lm) * 72 + ks2 * 32 + lg * 8];
                __builtin_amdgcn_s_setprio(1);
#pragma unroll
                for (int nv = 0; nv < 8; nv++) {
                    const int dv = nv * 16 + lm;
                    const bf16x8 vb = *(const bf16x8*)&Vs[dv * 64 +
                        ((ks2 * 32 + lg * 8) ^ ((dv & 7) << 3))];
#pragma unroll
                    for (int m = 0; m < 2; m++)
                        o[m][nv] = __builtin_amdgcn_mfma_f32_16x16x32_bf16(
                            pa[m], vb, o[m][nv], 0, 0, 0);
                }
                __builtin_amdgcn_s_setprio(0);
            }
        }

        // ---- epilogue: normalize, write bf16 [b*T+t][h*128+dv] ----
#pragma unroll
        for (int m = 0; m < 2; m++)
#pragma unroll
            for (int r = 0; r < 4; r++) {
                const float inv = 1.f / li[m][r];
                const int trow = t0 + w * 32 + m * 16 + lg * 4 + r;
                ushort_t* orow = OUT + (size_t)(b * T_ + trow) * 2048 + h * 128 + lm;
#pragma unroll
                for (int nv = 0; nv < 8; nv++)
                    orow[nv * 16] = f2bf(o[m][nv][r] * inv);
            }
    }
}

// ---------------------------------------------------------------------------
extern "C" void kernel_launch(void* const* d_in, const int* in_sizes, int n_in,
                              void* d_out, int out_size, void* d_ws, size_t ws_size,
                              hipStream_t stream)
{
    const float* x       = (const float*)d_in[0];
    const float* w_q_sem = (const float*)d_in[1];
    const float* w_k_sem = (const float*)d_in[2];
    const float* w_q_geo = (const float*)d_in[3];
    const float* w_k_geo = (const float*)d_in[4];
    const float* w_v     = (const float*)d_in[5];
    const float* w_out   = (const float*)d_in[6];
    const float* glogit  = (const float*)d_in[7];
    const float* gw      = (const float*)d_in[8];
    float* out = (float*)d_out;

    const int M = B_ * T_;  // 4096
    const size_t MB8 = (size_t)8 * 1024 * 1024;

    // workspace (96.75 MB):
    ushort_t* xbf = (ushort_t*)d_ws;       // [4096][2048] bf16
    ushort_t* WT  = xbf + MB8;             // up to [4096][2048] bf16 (weightsT)
    ushort_t* Qb  = WT + MB8;              // [bh][t][128]
    ushort_t* Kb  = Qb + MB8;              // [bh][t][128] swizzled
    ushort_t* Vt  = Kb + MB8;              // [bh][128][2048] swizzled V^T
    ushort_t* Vbb = Vt + MB8;              // [4096][2048] bf16 V (row-major)
    float* GATE   = (float*)(Vbb + MB8);   // [4096][16]
    float2* TAB   = (float2*)(GATE + 65536); // [2048][32]
    ushort_t* ATTbf = Vbb;                 // alias: Vbb dead after prep_v

    dim3 blk(256);

    cvt_gate_kernel<<<dim3(M), blk, 0, stream>>>(x, gw, glogit, xbf, GATE);
    rope_table<<<dim3(256), blk, 0, stream>>>(TAB);
    cvt_tr4_bf16<<<dim3(16, 32, 4), blk, 0, stream>>>(w_q_sem, w_k_sem, w_q_geo, w_k_geo, WT);

    // fused QK projection + rope + gate + swizzle -> Qb, Kb
    gemm_qk_fused<<<dim3(32, 32), blk, 0, stream>>>(xbf, WT, GATE, TAB, Qb, Kb, 2048);

    // V projection (bf16 out) + transpose/swizzle
    cvt_tr_bf16<<<dim3(32, 32), blk, 0, stream>>>(w_v, WT, 2048, 2048);
    gemm_bf16_bf16out<<<dim3(16, 32), blk, 0, stream>>>(xbf, WT, Vbb, 2048, 2048);
    prep_v<<<dim3(T_ / 64, 2, 32), blk, 0, stream>>>(Vbb, Vt);

    attn_mfma<<<dim3(8, 32), blk, 0, stream>>>(Qb, Kb, Vt, ATTbf);

    cvt_tr_bf16<<<dim3(32, 32), blk, 0, stream>>>(w_out, WT, 2048, 2048);
    gemm_bf16_bt<<<dim3(16, 32), blk, 0, stream>>>(ATTbf, WT, out, 2048, 2048);
}

// Round 7
// 538.820 us; speedup vs baseline: 1.0344x; 1.0344x over previous
//
#include <hip/hip_runtime.h>
#include <hip/hip_bf16.h>
#include <math.h>

#define B_ 2
#define T_ 2048
#define D_ 2048
#define H_ 16

typedef __attribute__((ext_vector_type(8))) short bf16x8;
typedef __attribute__((ext_vector_type(4))) float f32x4;
typedef unsigned short ushort_t;

// fp32 -> bf16 bits, round-to-nearest-even
__device__ __forceinline__ ushort_t f2bf(float f) {
    unsigned int u = __float_as_uint(f);
    u += 0x7fffu + ((u >> 16) & 1u);
    return (ushort_t)(u >> 16);
}

__device__ __forceinline__ void gl_lds16(const void* g, void* l) {
    __builtin_amdgcn_global_load_lds(
        (const __attribute__((address_space(1))) void*)g,
        (__attribute__((address_space(3))) void*)l, 16, 0, 0);
}

// ---------------------------------------------------------------------------
// fused x cvt + gate: one block per token row.
//   xbf[row][:] = bf16(x[row][:])
//   gate[row][h] = sigmoid(gate_logit[h] + x[row,:] . gate_w[:,h])
// ---------------------------------------------------------------------------
__global__ __launch_bounds__(256) void cvt_gate_kernel(
    const float* __restrict__ x, const float* __restrict__ gw,
    const float* __restrict__ glogit,
    ushort_t* __restrict__ xbf, float* __restrict__ gate)
{
    __shared__ float xs[2048];
    __shared__ float red[256];
    const int row = blockIdx.x, tid = threadIdx.x;

    const float4 a = *(const float4*)(x + (size_t)row * 2048 + tid * 8);
    const float4 b = *(const float4*)(x + (size_t)row * 2048 + tid * 8 + 4);
    unsigned int r0 = (unsigned int)f2bf(a.x) | ((unsigned int)f2bf(a.y) << 16);
    unsigned int r1 = (unsigned int)f2bf(a.z) | ((unsigned int)f2bf(a.w) << 16);
    unsigned int r2 = (unsigned int)f2bf(b.x) | ((unsigned int)f2bf(b.y) << 16);
    unsigned int r3 = (unsigned int)f2bf(b.z) | ((unsigned int)f2bf(b.w) << 16);
    *(uint4*)(xbf + (size_t)row * 2048 + tid * 8) = make_uint4(r0, r1, r2, r3);
    *(float4*)&xs[tid * 8] = a;
    *(float4*)&xs[tid * 8 + 4] = b;
    __syncthreads();

    const int h = tid & 15, chunk = tid >> 4;
    float acc = 0.f;
#pragma unroll 4
    for (int d0 = 0; d0 < 128; d0++) {
        const int d = chunk * 128 + d0;
        acc += xs[d] * gw[d * 16 + h];
    }
    red[tid] = acc;
    __syncthreads();
    for (int st = 8; st >= 1; st >>= 1) {
        if (chunk < st) red[chunk * 16 + h] += red[(chunk + st) * 16 + h];
        __syncthreads();
    }
    if (tid < 16) gate[row * 16 + tid] = 1.f / (1.f + expf(-(glogit[tid] + red[tid])));
}

// ---------------------------------------------------------------------------
// rope cos/sin table: tab[t*32+j] = (cos, sin)(t * 10000^(-j/32))
// ---------------------------------------------------------------------------
__global__ __launch_bounds__(256) void rope_table(float2* __restrict__ tab)
{
    const int gid = blockIdx.x * 256 + threadIdx.x;  // 65536
    const int j = gid & 31, t = gid >> 5;
    const float invf = exp2f((float)j * -0.41524101186091903f);
    const float ang = (float)t * invf;
    tab[gid] = make_float2(cosf(ang), sinf(ang));
}

// ---------------------------------------------------------------------------
// ALL weight transposes in one launch (fp32 [K][N] -> bf16 [N][K], K=2048).
// z=0..3: the four QK projection weights ([2048][1024]) -> WTqk rows z*1024..
// z=4..5: w_v   column halves ([2048][2048])            -> WTv
// z=6..7: w_out column halves                           -> WTo
// ---------------------------------------------------------------------------
__global__ __launch_bounds__(256) void cvt_wt_all(
    const float* __restrict__ w_qs, const float* __restrict__ w_ks,
    const float* __restrict__ w_qg, const float* __restrict__ w_kg,
    const float* __restrict__ w_v,  const float* __restrict__ w_o,
    ushort_t* __restrict__ WTqk, ushort_t* __restrict__ WTv,
    ushort_t* __restrict__ WTo)
{
    __shared__ float t[64][65];
    const int z = blockIdx.z;
    const float* in;
    ushort_t* outp;
    int srcN, colbase;
    if (z < 4) {
        in = (z == 0) ? w_qs : (z == 1) ? w_ks : (z == 2) ? w_qg : w_kg;
        outp = WTqk + (size_t)z * 1024 * 2048;
        srcN = 1024; colbase = 0;
    } else {
        in = (z < 6) ? w_v : w_o;
        outp = (z < 6) ? WTv : WTo;
        srcN = 2048; colbase = (z & 1) * 1024;
    }
    const int n0 = colbase + blockIdx.x * 64, k0 = blockIdx.y * 64;
    const int tx = threadIdx.x & 63, ty = threadIdx.x >> 6;
#pragma unroll
    for (int i = 0; i < 16; i++) {
        const int r = i * 4 + ty;
        t[r][tx] = in[(size_t)(k0 + r) * srcN + n0 + tx];
    }
    __syncthreads();
#pragma unroll
    for (int i = 0; i < 16; i++) {
        const int nn = i * 4 + ty;
        outp[(size_t)(n0 + nn) * 2048 + k0 + tx] = f2bf(t[tx][nn]);
    }
}

// ---------------------------------------------------------------------------
// Shared GEMM core (m97 structure): acc = A[M,K] @ BT[N,K]^T, 128x128 tile.
// NOTE: no setprio here — measured −12% on this 2-phase structure (round 6).
// ---------------------------------------------------------------------------
__device__ __forceinline__ void gemm_core(
    const ushort_t* __restrict__ Ab, const ushort_t* __restrict__ BTb,
    int K, int row0, int col0,
    ushort_t* As, ushort_t* Bs, f32x4 (&acc)[4][4], int w, int lane)
{
    const int lm = lane & 15, lk = (lane >> 4) << 3;
    const int wr = w >> 1, wc = w & 1;
#pragma unroll
    for (int m = 0; m < 4; m++)
#pragma unroll
        for (int n = 0; n < 4; n++) {
            acc[m][n][0] = 0.f; acc[m][n][1] = 0.f;
            acc[m][n][2] = 0.f; acc[m][n][3] = 0.f;
        }

    for (int k0 = 0; k0 < K; k0 += 32) {
        __syncthreads();
#pragma unroll
        for (int i = 0; i < 2; i++) {
            const int chunk = i * 4 + w;
            const int idx = chunk * 64 + lane;
            const int r = idx >> 2;
            const int c = (idx & 3) << 3;
            gl_lds16(Ab + (size_t)(row0 + r) * K + k0 + c, As + chunk * 512);
            gl_lds16(BTb + (size_t)(col0 + r) * K + k0 + c, Bs + chunk * 512);
        }
        __syncthreads();

        bf16x8 av[4], bv[4];
#pragma unroll
        for (int m = 0; m < 4; m++)
            av[m] = *(const bf16x8*)&As[(wr * 64 + m * 16 + lm) * 32 + lk];
#pragma unroll
        for (int n = 0; n < 4; n++)
            bv[n] = *(const bf16x8*)&Bs[(wc * 64 + n * 16 + lm) * 32 + lk];
#pragma unroll
        for (int m = 0; m < 4; m++)
#pragma unroll
            for (int n = 0; n < 4; n++)
                acc[m][n] = __builtin_amdgcn_mfma_f32_16x16x32_bf16(
                    av[m], bv[n], acc[m][n], 0, 0, 0);
    }
}

// bijective XCD swizzle (nwg % 8 == 0 for all our grids)
__device__ __forceinline__ void xcd_tile(int& row0, int& col0)
{
    const int o = blockIdx.y * gridDim.x + blockIdx.x;
    const int nwg = gridDim.x * gridDim.y;
    const int s = (o & 7) * (nwg >> 3) + (o >> 3);
    col0 = (s % gridDim.x) << 7;
    row0 = (s / gridDim.x) << 7;
}

// ---------------------------------------------------------------------------
// gemm_bf16_bt: fp32 row-major C (final output projection)
// ---------------------------------------------------------------------------
__global__ __launch_bounds__(256) void gemm_bf16_bt(
    const ushort_t* __restrict__ Ab, const ushort_t* __restrict__ BTb,
    float* __restrict__ C, int N, int K)
{
    __shared__ ushort_t As[4096];
    __shared__ ushort_t Bs[4096];
    const int tid = threadIdx.x;
    const int w = tid >> 6, lane = tid & 63;
    int row0, col0;
    xcd_tile(row0, col0);
    f32x4 acc[4][4];
    gemm_core(Ab, BTb, K, row0, col0, As, Bs, acc, w, lane);

    const int wr = w >> 1, wc = w & 1;
    const int lm = lane & 15;
#pragma unroll
    for (int m = 0; m < 4; m++) {
        const int rowb = row0 + wr * 64 + m * 16 + ((lane >> 4) << 2);
#pragma unroll
        for (int n = 0; n < 4; n++) {
            const int col = col0 + wc * 64 + n * 16 + lm;
#pragma unroll
            for (int r = 0; r < 4; r++)
                C[(size_t)(rowb + r) * N + col] = acc[m][n][r];
        }
    }
}

// ---------------------------------------------------------------------------
// gemm_bf16_bf16out: bf16 row-major C (V projection)
// ---------------------------------------------------------------------------
__global__ __launch_bounds__(256) void gemm_bf16_bf16out(
    const ushort_t* __restrict__ Ab, const ushort_t* __restrict__ BTb,
    ushort_t* __restrict__ C, int N, int K)
{
    __shared__ ushort_t As[4096];
    __shared__ ushort_t Bs[4096];
    const int tid = threadIdx.x;
    const int w = tid >> 6, lane = tid & 63;
    int row0, col0;
    xcd_tile(row0, col0);
    f32x4 acc[4][4];
    gemm_core(Ab, BTb, K, row0, col0, As, Bs, acc, w, lane);

    const int wr = w >> 1, wc = w & 1;
    const int lm = lane & 15;
#pragma unroll
    for (int m = 0; m < 4; m++) {
        const int rowb = row0 + wr * 64 + m * 16 + ((lane >> 4) << 2);
#pragma unroll
        for (int n = 0; n < 4; n++) {
            const int col = col0 + wc * 64 + n * 16 + lm;
#pragma unroll
            for (int r = 0; r < 4; r++)
                C[(size_t)(rowb + r) * N + col] = f2bf(acc[m][n][r]);
        }
    }
}

// ---------------------------------------------------------------------------
// gemm_qk_fused: QK projection with fused rope/gate/bf16/K-swizzle epilogue.
// cols [0,1024)=qs, [1024,2048)=ks, [2048,3072)=qg, [3072,4096)=kg.
// ---------------------------------------------------------------------------
__global__ __launch_bounds__(256) void gemm_qk_fused(
    const ushort_t* __restrict__ Ab, const ushort_t* __restrict__ BTb,
    const float* __restrict__ GATE, const float2* __restrict__ tab,
    ushort_t* __restrict__ Qb, ushort_t* __restrict__ Kb, int K)
{
    __shared__ ushort_t As[4096];
    __shared__ ushort_t Bs[4096];
    const int tid = threadIdx.x;
    const int w = tid >> 6, lane = tid & 63;
    int row0, col0;
    xcd_tile(row0, col0);
    f32x4 acc[4][4];
    gemm_core(Ab, BTb, K, row0, col0, As, Bs, acc, w, lane);

    const int wr = w >> 1, wc = w & 1;
    const int lm = lane & 15, lg = lane >> 4;
    const int col_base = col0 + wc * 64;     // 64-aligned -> one head, one region
    const int region = col_base >> 10;       // 0=qs 1=ks 2=qg 3=kg
    const int h = (col_base >> 6) & 15;

#pragma unroll
    for (int m = 0; m < 4; m++) {
        const int rbase = row0 + wr * 64 + m * 16 + (lg << 2);
#pragma unroll
        for (int r = 0; r < 4; r++) {
            const int row = rbase + r;
            const int t = row & (T_ - 1);
            const int bq = row >> 11;
            const size_t obase = ((size_t)(bq * 16 + h) * 2048 + t) * 128;
            if (region == 0) {
                const float sc = GATE[row * 16 + h] * 0.125f;
#pragma unroll
                for (int n = 0; n < 4; n++)
                    Qb[obase + n * 16 + lm] = f2bf(acc[m][n][r] * sc);
            } else if (region == 1) {
                const int sw = (t & 7) << 3;
#pragma unroll
                for (int n = 0; n < 4; n++)
                    Kb[obase + ((n * 16 + lm) ^ sw)] = f2bf(acc[m][n][r]);
            } else if (region == 2) {
                const float sc = (1.f - GATE[row * 16 + h]) * 0.125f;
#pragma unroll
                for (int n = 0; n < 2; n++) {
                    const int j = n * 16 + lm;
                    const float2 cs = tab[t * 32 + j];
                    const float x1 = acc[m][n][r], x2 = acc[m][n + 2][r];
                    Qb[obase + 64 + j] = f2bf((x1 * cs.x - x2 * cs.y) * sc);
                    Qb[obase + 96 + j] = f2bf((x2 * cs.x + x1 * cs.y) * sc);
                }
            } else {
                const int sw = (t & 7) << 3;
#pragma unroll
                for (int n = 0; n < 2; n++) {
                    const int j = n * 16 + lm;
                    const float2 cs = tab[t * 32 + j];
                    const float x1 = acc[m][n][r], x2 = acc[m][n + 2][r];
                    Kb[obase + ((64 + j) ^ sw)] = f2bf(x1 * cs.x - x2 * cs.y);
                    Kb[obase + ((96 + j) ^ sw)] = f2bf(x2 * cs.x + x1 * cs.y);
                }
            }
        }
    }
}

// ---------------------------------------------------------------------------
// prep_v: Vbb bf16 [row][h*128+dv] -> Vt[bh][dv][t swizzled] bf16 (V^T).
// ---------------------------------------------------------------------------
__global__ __launch_bounds__(256) void prep_v(
    const ushort_t* __restrict__ Vbb, ushort_t* __restrict__ Vt)
{
    __shared__ ushort_t tile[64][65];
    const int t0 = blockIdx.x * 64, dv0 = blockIdx.y * 64, bh = blockIdx.z;
    const int b = bh >> 4, h = bh & 15;
    const int c = threadIdx.x & 63, rq = threadIdx.x >> 6;
#pragma unroll
    for (int i = 0; i < 16; i++) {
        const int r = i * 4 + rq;
        tile[r][c] = Vbb[(size_t)(b * T_ + t0 + r) * 2048 + h * 128 + dv0 + c];
    }
    __syncthreads();
#pragma unroll
    for (int i = 0; i < 16; i++) {
        const int dvr = i * 4 + rq;
        const int dv = dv0 + dvr;
        Vt[((size_t)bh * 128 + dv) * 2048 + t0 + (c ^ ((dv & 7) << 3))] = tile[c][dvr];
    }
}

// ---------------------------------------------------------------------------
// MFMA flash attention, causal-PAIRED: block (pair, bh) processes Q-tiles
// (15-pair) and (pair) sequentially -> every block does exactly 34 K-tiles.
// QBLK=128 (4 waves x 32 rows), KBLK=64, d=dv=128. Defer-max THR=8.
// setprio kept here: attn improved with it (round 6: dropped out of top-5).
// ---------------------------------------------------------------------------
__global__ __launch_bounds__(256, 2) void attn_mfma(
    const ushort_t* __restrict__ Qb, const ushort_t* __restrict__ Kb,
    const ushort_t* __restrict__ Vt, ushort_t* __restrict__ OUT)
{
    __shared__ ushort_t Ks[64 * 128];   // [key][d_sw]  16KB
    __shared__ ushort_t Vs[128 * 64];   // [dv][k_sw]   16KB
    __shared__ ushort_t Ps[4][32 * 72]; // per-wave P, row stride 72  18KB

    const int tid = threadIdx.x;
    const int w = tid >> 6, l = tid & 63;
    const int lg = l >> 4, lm = l & 15;
    const int bh = blockIdx.y;
    const int pair = blockIdx.x;        // 0..7
    const size_t hb = (size_t)bh * 2048 * 128;
    const int b = bh >> 4, h = bh & 15;
    ushort_t* pw = &Ps[w][0];

    for (int half = 0; half < 2; half++) {
        const int tile = (half == 0) ? (15 - pair) : pair;   // heavy first
        const int t0 = tile << 7;

        bf16x8 qf[2][4];
#pragma unroll
        for (int m = 0; m < 2; m++)
#pragma unroll
            for (int ks = 0; ks < 4; ks++)
                qf[m][ks] = *(const bf16x8*)(Qb + hb +
                    (size_t)(t0 + w * 32 + m * 16 + lm) * 128 + ks * 32 + lg * 8);

        f32x4 o[2][8];
        float mi[2][4], li[2][4];
#pragma unroll
        for (int m = 0; m < 2; m++) {
#pragma unroll
            for (int r = 0; r < 4; r++) { mi[m][r] = -1e30f; li[m][r] = 0.f; }
#pragma unroll
            for (int nv = 0; nv < 8; nv++) {
                o[m][nv][0] = 0.f; o[m][nv][1] = 0.f;
                o[m][nv][2] = 0.f; o[m][nv][3] = 0.f;
            }
        }

        const int nkt = 2 * tile + 2;
        for (int kt = 0; kt < nkt; kt++) {
            const int s0 = kt << 6;
            __syncthreads();
#pragma unroll
            for (int rr = 0; rr < 4; rr++) {
                const int chunk = rr * 4 + w;
                gl_lds16(Kb + hb + (size_t)(s0 + chunk * 4 + lg) * 128 + lm * 8,
                         Ks + chunk * 512);
            }
#pragma unroll
            for (int rr = 0; rr < 4; rr++) {
                const int chunk = rr * 4 + w;
                gl_lds16(Vt + hb + (size_t)(chunk * 8 + (l >> 3)) * 2048 + s0 + (l & 7) * 8,
                         Vs + chunk * 512);
            }
            __syncthreads();

            // ---- S = Q . K^T ----
            f32x4 sacc[2][4];
#pragma unroll
            for (int m = 0; m < 2; m++)
#pragma unroll
                for (int n = 0; n < 4; n++) {
                    sacc[m][n][0] = 0.f; sacc[m][n][1] = 0.f;
                    sacc[m][n][2] = 0.f; sacc[m][n][3] = 0.f;
                }
#pragma unroll
            for (int ks = 0; ks < 4; ks++) {
                bf16x8 bfr[4];
#pragma unroll
                for (int n = 0; n < 4; n++) {
                    const int key = n * 16 + lm;
                    const int d = ks * 32 + lg * 8;
                    bfr[n] = *(const bf16x8*)&Ks[key * 128 + (d ^ ((key & 7) << 3))];
                }
                __builtin_amdgcn_s_setprio(1);
#pragma unroll
                for (int m = 0; m < 2; m++)
#pragma unroll
                    for (int n = 0; n < 4; n++)
                        sacc[m][n] = __builtin_amdgcn_mfma_f32_16x16x32_bf16(
                            qf[m][ks], bfr[n], sacc[m][n], 0, 0, 0);
                __builtin_amdgcn_s_setprio(0);
            }

            if (kt >= nkt - 2) {
#pragma unroll
                for (int m = 0; m < 2; m++)
#pragma unroll
                    for (int n = 0; n < 4; n++)
#pragma unroll
                        for (int r = 0; r < 4; r++) {
                            const int rowt = t0 + w * 32 + m * 16 + lg * 4 + r;
                            const int colt = s0 + n * 16 + lm;
                            if (colt > rowt) sacc[m][n][r] = -1e30f;
                        }
            }

            // ---- online softmax (defer-max THR=8) + P -> LDS (bf16) ----
#pragma unroll
            for (int m = 0; m < 2; m++) {
#pragma unroll
                for (int r = 0; r < 4; r++) {
                    float mt = fmaxf(fmaxf(sacc[m][0][r], sacc[m][1][r]),
                                     fmaxf(sacc[m][2][r], sacc[m][3][r]));
                    mt = fmaxf(mt, __shfl_xor(mt, 1));
                    mt = fmaxf(mt, __shfl_xor(mt, 2));
                    mt = fmaxf(mt, __shfl_xor(mt, 4));
                    mt = fmaxf(mt, __shfl_xor(mt, 8));
                    const float miold = mi[m][r];
                    if (mt > miold + 8.f) {      // rescale path
                        const float alpha = __expf(miold - mt);
                        li[m][r] *= alpha;
#pragma unroll
                        for (int nv = 0; nv < 8; nv++) o[m][nv][r] *= alpha;
                        mi[m][r] = mt;
                    }
                    const float mcur = mi[m][r];
                    float rs = 0.f;
#pragma unroll
                    for (int n = 0; n < 4; n++) {
                        const float p = __expf(sacc[m][n][r] - mcur);
                        sacc[m][n][r] = p;
                        rs += p;
                    }
                    rs += __shfl_xor(rs, 1);
                    rs += __shfl_xor(rs, 2);
                    rs += __shfl_xor(rs, 4);
                    rs += __shfl_xor(rs, 8);
                    li[m][r] += rs;
#pragma unroll
                    for (int n = 0; n < 4; n++)
                        pw[(m * 16 + lg * 4 + r) * 72 + n * 16 + lm] = f2bf(sacc[m][n][r]);
                }
            }

            // ---- O += P @ V ----
#pragma unroll
            for (int ks2 = 0; ks2 < 2; ks2++) {
                bf16x8 pa[2];
#pragma unroll
                for (int m = 0; m < 2; m++)
                    pa[m] = *(const bf16x8*)&pw[(m * 16 + lm) * 72 + ks2 * 32 + lg * 8];
                __builtin_amdgcn_s_setprio(1);
#pragma unroll
                for (int nv = 0; nv < 8; nv++) {
                    const int dv = nv * 16 + lm;
                    const bf16x8 vb = *(const bf16x8*)&Vs[dv * 64 +
                        ((ks2 * 32 + lg * 8) ^ ((dv & 7) << 3))];
#pragma unroll
                    for (int m = 0; m < 2; m++)
                        o[m][nv] = __builtin_amdgcn_mfma_f32_16x16x32_bf16(
                            pa[m], vb, o[m][nv], 0, 0, 0);
                }
                __builtin_amdgcn_s_setprio(0);
            }
        }

        // ---- epilogue: normalize, write bf16 [b*T+t][h*128+dv] ----
#pragma unroll
        for (int m = 0; m < 2; m++)
#pragma unroll
            for (int r = 0; r < 4; r++) {
                const float inv = 1.f / li[m][r];
                const int trow = t0 + w * 32 + m * 16 + lg * 4 + r;
                ushort_t* orow = OUT + (size_t)(b * T_ + trow) * 2048 + h * 128 + lm;
#pragma unroll
                for (int nv = 0; nv < 8; nv++)
                    orow[nv * 16] = f2bf(o[m][nv][r] * inv);
            }
    }
}

// ---------------------------------------------------------------------------
extern "C" void kernel_launch(void* const* d_in, const int* in_sizes, int n_in,
                              void* d_out, int out_size, void* d_ws, size_t ws_size,
                              hipStream_t stream)
{
    const float* x       = (const float*)d_in[0];
    const float* w_q_sem = (const float*)d_in[1];
    const float* w_k_sem = (const float*)d_in[2];
    const float* w_q_geo = (const float*)d_in[3];
    const float* w_k_geo = (const float*)d_in[4];
    const float* w_v     = (const float*)d_in[5];
    const float* w_out   = (const float*)d_in[6];
    const float* glogit  = (const float*)d_in[7];
    const float* gw      = (const float*)d_in[8];
    float* out = (float*)d_out;

    const int M = B_ * T_;  // 4096
    const size_t MB8 = (size_t)8 * 1024 * 1024;   // 8M ushorts = 16 MB

    // workspace (~113 MB):
    ushort_t* xbf  = (ushort_t*)d_ws;        // [4096][2048] bf16
    ushort_t* WTqk = xbf + MB8;              // [4096][2048] bf16 (qs|ks|qg|kg)^T
    ushort_t* WTv  = WTqk + MB8;             // [2048][2048] bf16 w_v^T
    ushort_t* WTo  = WTv + MB8 / 2;          // [2048][2048] bf16 w_out^T
    ushort_t* Qb   = WTo + MB8 / 2;          // [bh][t][128]
    ushort_t* Kb   = Qb + MB8;               // [bh][t][128] swizzled
    ushort_t* Vt   = Kb + MB8;               // [bh][128][2048] swizzled V^T
    ushort_t* Vbb  = Vt + MB8;               // [4096][2048] bf16 V (row-major)
    float* GATE    = (float*)(Vbb + MB8);    // [4096][16]
    float2* TAB    = (float2*)(GATE + 65536);// [2048][32]
    ushort_t* ATTbf = Vbb;                   // alias: Vbb dead after prep_v

    dim3 blk(256);

    cvt_gate_kernel<<<dim3(M), blk, 0, stream>>>(x, gw, glogit, xbf, GATE);
    rope_table<<<dim3(256), blk, 0, stream>>>(TAB);
    cvt_wt_all<<<dim3(16, 32, 8), blk, 0, stream>>>(
        w_q_sem, w_k_sem, w_q_geo, w_k_geo, w_v, w_out, WTqk, WTv, WTo);

    // fused QK projection + rope + gate + swizzle -> Qb, Kb
    gemm_qk_fused<<<dim3(32, 32), blk, 0, stream>>>(xbf, WTqk, GATE, TAB, Qb, Kb, 2048);

    // V projection (bf16 out) + transpose/swizzle
    gemm_bf16_bf16out<<<dim3(16, 32), blk, 0, stream>>>(xbf, WTv, Vbb, 2048, 2048);
    prep_v<<<dim3(T_ / 64, 2, 32), blk, 0, stream>>>(Vbb, Vt);

    attn_mfma<<<dim3(8, 32), blk, 0, stream>>>(Qb, Kb, Vt, ATTbf);

    // output projection (WTo already prepared -> starts immediately)
    gemm_bf16_bt<<<dim3(16, 32), blk, 0, stream>>>(ATTbf, WTo, out, 2048, 2048);
}